// Round 5
// baseline (156.022 us; speedup 1.0000x reference)
//
#include <hip/hip_runtime.h>
#include <hip/hip_bf16.h>
#include <cstdint>
#include <cstddef>

#define Bb 4
#define Tt 2048
#define Ee 512
#define Hh 8
#define Dd 64
#define HD 512
#define BT 8192

typedef __bf16 bf16x8 __attribute__((ext_vector_type(8)));
typedef __bf16 bf16x4 __attribute__((ext_vector_type(4)));
typedef float f32x4 __attribute__((ext_vector_type(4)));

__device__ __forceinline__ f32x4 mfma16(bf16x8 a, bf16x8 b, f32x4 c) {
  return __builtin_amdgcn_mfma_f32_16x16x32_bf16(a, b, c, 0, 0, 0);
}

typedef __attribute__((address_space(3))) uint32_t lds_u32_t;
typedef const __attribute__((address_space(1))) uint32_t glb_u32_t;
__device__ __forceinline__ void gload16(const void* g, void* l) {
  // wave-uniform LDS base; HW adds lane*16. Global src is per-lane.
  __builtin_amdgcn_global_load_lds((glb_u32_t*)g, (lds_u32_t*)l, 16, 0, 0);
}

// ---- weight conversion: 4 x [512x512] f32 -> bf16 ----
__global__ void cvt_w_kernel(const float* __restrict__ wq, const float* __restrict__ wk,
                             const float* __restrict__ wv, const float* __restrict__ wo,
                             __bf16* __restrict__ dst) {
  int i = (blockIdx.x * 256 + threadIdx.x) * 4;
  int a = i >> 18;
  int off = i & ((1 << 18) - 1);
  const float* src = (a == 0) ? wq : (a == 1) ? wk : (a == 2) ? wv : wo;
  float4 f = *(const float4*)(src + off);
  bf16x4 o;
  o[0] = (__bf16)f.x; o[1] = (__bf16)f.y; o[2] = (__bf16)f.z; o[3] = (__bf16)f.w;
  *(bf16x4*)(dst + i) = o;
}

// ---- QKV projection GEMM. z: 0=Q->qh (pre-scaled by 0.125*log2e), 1=K->kh, 2=V->vt[B,H,D,T] ----
__global__ __launch_bounds__(256)
void gemm_qkv_kernel(const float* __restrict__ Aq, const float* __restrict__ Ak,
                     const float* __restrict__ Av, const __bf16* __restrict__ Wall,
                     __bf16* __restrict__ qh, __bf16* __restrict__ kh, __bf16* __restrict__ vt) {
  const int pz = blockIdx.z;
  const float* A = (pz == 0) ? Aq : (pz == 1) ? Ak : Av;
  const __bf16* Bw = Wall + (size_t)pz * HD * Ee;
  const int row0 = blockIdx.y * 128;
  const int col0 = blockIdx.x * 128;

  __shared__ __align__(16) __bf16 As[128 * 32];
  __shared__ __align__(16) __bf16 Bs[128 * 32];
  char* As8 = (char*)As;
  char* Bs8 = (char*)Bs;

  const int tid = threadIdx.x;
  const int l = tid & 63, w = tid >> 6;
  const int ln = l & 15, lg = l >> 4;
  const int wr = (w >> 1) * 64, wc = (w & 1) * 64;

  const int sr = tid >> 1;
  const int sce = (tid & 1) * 16;
  const int sbyte = sr * 64 + sce * 2;
  const int swz = (sr & 7) << 4;

  f32x4 acc[4][4] = {};

  for (int kt = 0; kt < Ee; kt += 32) {
    const float* ag = A + (size_t)(row0 + sr) * Ee + kt + sce;
    float4 a0 = *(const float4*)(ag);
    float4 a1 = *(const float4*)(ag + 4);
    float4 a2 = *(const float4*)(ag + 8);
    float4 a3 = *(const float4*)(ag + 12);
    const __bf16* bg = Bw + (size_t)(col0 + sr) * Ee + kt + sce;
    bf16x8 b0 = *(const bf16x8*)(bg);
    bf16x8 b1 = *(const bf16x8*)(bg + 8);
    bf16x8 c0, c1;
    c0[0] = (__bf16)a0.x; c0[1] = (__bf16)a0.y; c0[2] = (__bf16)a0.z; c0[3] = (__bf16)a0.w;
    c0[4] = (__bf16)a1.x; c0[5] = (__bf16)a1.y; c0[6] = (__bf16)a1.z; c0[7] = (__bf16)a1.w;
    c1[0] = (__bf16)a2.x; c1[1] = (__bf16)a2.y; c1[2] = (__bf16)a2.z; c1[3] = (__bf16)a2.w;
    c1[4] = (__bf16)a3.x; c1[5] = (__bf16)a3.y; c1[6] = (__bf16)a3.z; c1[7] = (__bf16)a3.w;
    __syncthreads();
    *(bf16x8*)(As8 + ((sbyte) ^ swz)) = c0;
    *(bf16x8*)(As8 + ((sbyte + 16) ^ swz)) = c1;
    *(bf16x8*)(Bs8 + ((sbyte) ^ swz)) = b0;
    *(bf16x8*)(Bs8 + ((sbyte + 16) ^ swz)) = b1;
    __syncthreads();
    bf16x8 af[4], bfr[4];
#pragma unroll
    for (int mi = 0; mi < 4; mi++) {
      int r = wr + mi * 16 + ln;
      af[mi] = *(const bf16x8*)(As8 + ((r * 64 + lg * 16) ^ ((r & 7) << 4)));
    }
#pragma unroll
    for (int ni = 0; ni < 4; ni++) {
      int r = wc + ni * 16 + ln;
      bfr[ni] = *(const bf16x8*)(Bs8 + ((r * 64 + lg * 16) ^ ((r & 7) << 4)));
    }
#pragma unroll
    for (int mi = 0; mi < 4; mi++)
#pragma unroll
      for (int ni = 0; ni < 4; ni++)
        acc[mi][ni] = mfma16(af[mi], bfr[ni], acc[mi][ni]);
  }

  // fold 1/sqrt(D)*log2(e) into Q so attention softmax can use exp2 directly
  const float sc = (pz == 0) ? 0.18033688011112042f : 1.0f;
#pragma unroll
  for (int mi = 0; mi < 4; mi++) {
    const int rowb = row0 + wr + mi * 16 + lg * 4;
    const int bb = rowb >> 11;
    const int t0 = rowb & (Tt - 1);
#pragma unroll
    for (int ni = 0; ni < 4; ni++) {
      const int colb = col0 + wc + ni * 16 + ln;
      const int hh = colb >> 6;
      const int dd = colb & 63;
      if (pz == 2) {
        bf16x4 pk;
#pragma unroll
        for (int r = 0; r < 4; r++) pk[r] = (__bf16)acc[mi][ni][r];
        *(bf16x4*)(vt + ((size_t)(bb * Hh + hh) * Dd + dd) * Tt + t0) = pk;
      } else {
        __bf16* dstp = (pz == 0 ? qh : kh) + ((size_t)(bb * Hh + hh) * Tt + t0) * Dd + dd;
#pragma unroll
        for (int r = 0; r < 4; r++) dstp[(size_t)r * Dd] = (__bf16)(acc[mi][ni][r] * sc);
      }
    }
  }
}

// ---- flash attention pass 1: QBLK=128 (4 waves x 32 q-rows, 2 Q frags/wave),
// KVBLK=64, LDS-staged K/V double-buffered, swapped QK^T, exp2 softmax, defer-max.
// grid: (chunk 2, qt 16, bh 32). K/V LDS fragments shared across the 2 Q frags. ----
__global__ __launch_bounds__(256)
void attn1_kernel(const __bf16* __restrict__ qh, const __bf16* __restrict__ kh,
                  const __bf16* __restrict__ vt, __bf16* __restrict__ opart,
                  float* __restrict__ mpart, float* __restrict__ lpart) {
  const int ck = blockIdx.x;
  const int qt = blockIdx.y;
  const int bh = blockIdx.z;
  const int nt = qt * 2 + 2;              // causal tiles needed for rows < (qt+1)*128
  const int t0 = ck * 16;
  const int tend = (nt < t0 + 16) ? nt : (t0 + 16);
  if (t0 >= tend) return;

  __shared__ __align__(16) char Kb[2][8192];  // [64 s][64 d] bf16, XOR-swizzled rows
  __shared__ __align__(16) char Vb[2][8192];  // [64 d][64 t] bf16, XOR-swizzled rows
  __shared__ __align__(16) char Pb[4][4096];  // per-wave 2x[16 q][64 k] bf16, swizzled

  const int tid = threadIdx.x;
  const int l = tid & 63, w = tid >> 6;
  const int ln = l & 15, lg = l >> 4;

  const char* Kg = (const char*)(kh + (size_t)bh * Tt * Dd);
  const char* Vg = (const char*)(vt + (size_t)bh * Dd * Tt);
  const __bf16* Q = qh + (size_t)bh * Tt * Dd;
  const int qr = qt * 128 + w * 32;       // wave's first q row (2 frags of 16)

  const int rsub = l >> 3;                 // 0..7
  const int csw = ((l & 7) ^ rsub) * 16;   // pre-swizzled 16B column
  const int krow = w * 16 + rsub;

  // prologue: stage tile t0 into buffer 0
  {
    const char* kt = Kg + (size_t)t0 * 8192;
    const char* vtile = Vg + (size_t)t0 * 128;
    char* kb = (char*)Kb[0] + w * 2048;
    char* vb = (char*)Vb[0] + w * 2048;
    gload16(kt + krow * 128 + csw, kb);
    gload16(kt + (krow + 8) * 128 + csw, kb + 1024);
    gload16(vtile + (size_t)krow * 4096 + csw, vb);
    gload16(vtile + (size_t)(krow + 8) * 4096 + csw, vb + 1024);
  }

  bf16x8 qf[2][2];
#pragma unroll
  for (int qi = 0; qi < 2; qi++)
#pragma unroll
    for (int kk = 0; kk < 2; kk++)
      qf[qi][kk] = *(const bf16x8*)(Q + (size_t)(qr + qi * 16 + ln) * Dd + kk * 32 + lg * 8);

  f32x4 oacc[2][4] = {};
  float mr[2] = {-1e30f, -1e30f}, sruml[2] = {0.f, 0.f};  // per-lane q = qr+qi*16+ln
  char* P8 = Pb[w];
  const int swz = (ln & 7) << 4;

  for (int st = t0; st < tend; ++st) {
    const int cur = (st - t0) & 1;
    asm volatile("s_waitcnt vmcnt(0)" ::: "memory");  // own quarter of tile st landed
    __builtin_amdgcn_s_barrier();                     // all waves' quarters landed
    __builtin_amdgcn_sched_barrier(0);
    if (st + 1 < tend) {  // prefetch next tile into other buffer
      const char* kt = Kg + (size_t)(st + 1) * 8192;
      const char* vtile = Vg + (size_t)(st + 1) * 128;
      char* kb = (char*)Kb[cur ^ 1] + w * 2048;
      char* vb = (char*)Vb[cur ^ 1] + w * 2048;
      gload16(kt + krow * 128 + csw, kb);
      gload16(kt + (krow + 8) * 128 + csw, kb + 1024);
      gload16(vtile + (size_t)krow * 4096 + csw, vb);
      gload16(vtile + (size_t)(krow + 8) * 4096 + csw, vb + 1024);
    }
    const char* KB = Kb[cur];
    const char* VB = Vb[cur];
    const int s0 = st * 64;

    // swapped QK^T: sacc[qi][ni] holds S[k=s0+ni*16+lg*4+r][q=qr+qi*16+ln]
    f32x4 sacc[2][4] = {};
    __builtin_amdgcn_s_setprio(1);
#pragma unroll
    for (int kk = 0; kk < 2; kk++) {
#pragma unroll
      for (int ni = 0; ni < 4; ni++) {
        bf16x8 kf = *(const bf16x8*)(KB + (ni * 16 + ln) * 128 + (((kk * 4 + lg) ^ (ln & 7)) * 16));
        sacc[0][ni] = mfma16(kf, qf[0][kk], sacc[0][ni]);
        sacc[1][ni] = mfma16(kf, qf[1][kk], sacc[1][ni]);
      }
    }
    __builtin_amdgcn_s_setprio(0);

#pragma unroll
    for (int qi = 0; qi < 2; qi++) {
      if (s0 + 63 > qr + qi * 16) {  // tile reaches past this frag's first row: mask k > q
#pragma unroll
        for (int ni = 0; ni < 4; ni++)
#pragma unroll
          for (int r = 0; r < 4; r++)
            if ((s0 + ni * 16 + lg * 4 + r) > (qr + qi * 16 + ln)) sacc[qi][ni][r] = -1e30f;
      }
    }

#pragma unroll
    for (int qi = 0; qi < 2; qi++) {
      // row max: in-lane over 16, then across lg (2 shfl steps)
      f32x4 m4 = sacc[qi][0];
#pragma unroll
      for (int ni = 1; ni < 4; ni++)
#pragma unroll
        for (int r = 0; r < 4; r++) m4[r] = fmaxf(m4[r], sacc[qi][ni][r]);
      float pmax = fmaxf(fmaxf(m4[0], m4[1]), fmaxf(m4[2], m4[3]));
      pmax = fmaxf(pmax, __shfl_xor(pmax, 16, 64));
      pmax = fmaxf(pmax, __shfl_xor(pmax, 32, 64));

      // defer-max (log2 units, THR=11 -> P bounded by 2^11)
      if (__any(pmax > mr[qi] + 11.0f)) {
        float mnew = fmaxf(mr[qi], pmax);
        float facq = exp2f(mr[qi] - mnew);
        mr[qi] = mnew;
        sruml[qi] *= facq;
#pragma unroll
        for (int r = 0; r < 4; r++) {
          float fr = __shfl(facq, lg * 4 + r, 64);  // fac for oacc's q-row
#pragma unroll
          for (int nd = 0; nd < 4; nd++) oacc[qi][nd][r] *= fr;
        }
      }

      // P = exp2(S - m), row sum
      float rsum = 0.f;
#pragma unroll
      for (int ni = 0; ni < 4; ni++)
#pragma unroll
        for (int r = 0; r < 4; r++) {
          float p = exp2f(sacc[qi][ni][r] - mr[qi]);
          sacc[qi][ni][r] = p;
          rsum += p;
        }
      rsum += __shfl_xor(rsum, 16, 64);
      rsum += __shfl_xor(rsum, 32, 64);
      sruml[qi] += rsum;

      // P -> per-wave LDS, [q=ln][k] rows, b64 packed writes (4 consecutive k)
#pragma unroll
      for (int ni = 0; ni < 4; ni++) {
        bf16x4 pk;
#pragma unroll
        for (int r = 0; r < 4; r++) pk[r] = (__bf16)sacc[qi][ni][r];
        *(bf16x4*)(P8 + qi * 2048 + ((ln * 128 + ni * 32 + lg * 8) ^ swz)) = pk;
      }
    }
    asm volatile("s_waitcnt lgkmcnt(0)" ::: "memory");
    __builtin_amdgcn_sched_barrier(0);

    // PV: A = P (row=q, k contiguous), B = V^T rows (d); V frag shared across frags
    __builtin_amdgcn_s_setprio(1);
#pragma unroll
    for (int kk = 0; kk < 2; kk++) {
      bf16x8 pf0 = *(const bf16x8*)(P8 + ((ln * 128 + kk * 64 + lg * 16) ^ swz));
      bf16x8 pf1 = *(const bf16x8*)(P8 + 2048 + ((ln * 128 + kk * 64 + lg * 16) ^ swz));
#pragma unroll
      for (int nd = 0; nd < 4; nd++) {
        bf16x8 vf = *(const bf16x8*)(VB + (nd * 16 + ln) * 128 + (((kk * 4 + lg) ^ (ln & 7)) * 16));
        oacc[0][nd] = mfma16(pf0, vf, oacc[0][nd]);
        oacc[1][nd] = mfma16(pf1, vf, oacc[1][nd]);
      }
    }
    __builtin_amdgcn_s_setprio(0);
    asm volatile("s_waitcnt lgkmcnt(0)" ::: "memory");  // P reads done before next overwrite
    __builtin_amdgcn_sched_barrier(0);
  }

  // epilogue: unnormalized O (bf16) + m,l (f32, log2 units)
  const int cb = ck * 32 + bh;
#pragma unroll
  for (int qi = 0; qi < 2; qi++) {
#pragma unroll
    for (int nd = 0; nd < 4; nd++)
#pragma unroll
      for (int r = 0; r < 4; r++) {
        int t = qr + qi * 16 + lg * 4 + r;
        opart[((size_t)cb * Tt + t) * 64 + nd * 16 + ln] = (__bf16)oacc[qi][nd][r];
      }
    if (l < 16) {
      mpart[(size_t)cb * Tt + qr + qi * 16 + l] = mr[qi];
      lpart[(size_t)cb * Tt + qr + qi * 16 + l] = sruml[qi];
    }
  }
}

// ---- flash attention pass 2: combine 2 chunks (log2-units m), normalize ----
__global__ __launch_bounds__(256)
void attn2_kernel(const __bf16* __restrict__ opart, const float* __restrict__ mpart,
                  const float* __restrict__ lpart, __bf16* __restrict__ att) {
  int idx = blockIdx.x * 256 + threadIdx.x;  // row id over [bh=32][t=2048]
  int bh = idx >> 11, t = idx & (Tt - 1);
  int b = bh >> 3, h = bh & 7;
  const __bf16* o0 = opart + ((size_t)bh * Tt + t) * 64;
  __bf16* dst = att + ((size_t)(b * Tt + t)) * HD + h * 64;
  float m0 = mpart[(size_t)bh * Tt + t];
  float l0 = lpart[(size_t)bh * Tt + t];
  if (t >= 1024) {
    const __bf16* o1 = o0 + (size_t)32 * Tt * 64;
    float m1 = mpart[(size_t)(32 + bh) * Tt + t];
    float l1 = lpart[(size_t)(32 + bh) * Tt + t];
    float M = fmaxf(m0, m1);
    float e0 = exp2f(m0 - M), e1 = exp2f(m1 - M);
    float den = l0 * e0 + l1 * e1;
    float a0 = e0 / den, a1 = e1 / den;
#pragma unroll
    for (int j = 0; j < 8; j++) {
      bf16x8 v0 = ((const bf16x8*)o0)[j];
      bf16x8 v1 = ((const bf16x8*)o1)[j];
      bf16x8 o;
#pragma unroll
      for (int e = 0; e < 8; e++)
        o[e] = (__bf16)((float)v0[e] * a0 + (float)v1[e] * a1);
      ((bf16x8*)dst)[j] = o;
    }
  } else {
    float a0 = 1.f / l0;
#pragma unroll
    for (int j = 0; j < 8; j++) {
      bf16x8 v0 = ((const bf16x8*)o0)[j];
      bf16x8 o;
#pragma unroll
      for (int e = 0; e < 8; e++)
        o[e] = (__bf16)((float)v0[e] * a0);
      ((bf16x8*)dst)[j] = o;
    }
  }
}

// ---- output projection: att[8192x512] bf16 x Wo[512x512] bf16 ([N][K]) + bo -> f32 ----
__global__ __launch_bounds__(256)
void gemm_out_kernel(const __bf16* __restrict__ att, const __bf16* __restrict__ Wo,
                     const float* __restrict__ bo, float* __restrict__ out) {
  const int row0 = blockIdx.y * 128;
  const int col0 = blockIdx.x * 128;
  __shared__ __align__(16) __bf16 As[128 * 32];
  __shared__ __align__(16) __bf16 Bs[128 * 32];
  char* As8 = (char*)As;
  char* Bs8 = (char*)Bs;
  const int tid = threadIdx.x;
  const int l = tid & 63, w = tid >> 6;
  const int ln = l & 15, lg = l >> 4;
  const int wr = (w >> 1) * 64, wc = (w & 1) * 64;
  const int sr = tid >> 1;
  const int sce = (tid & 1) * 16;
  const int sbyte = sr * 64 + sce * 2;
  const int swz = (sr & 7) << 4;
  f32x4 acc[4][4] = {};

  for (int kt = 0; kt < HD; kt += 32) {
    const __bf16* ag = att + (size_t)(row0 + sr) * HD + kt + sce;
    bf16x8 a0 = *(const bf16x8*)(ag);
    bf16x8 a1 = *(const bf16x8*)(ag + 8);
    const __bf16* bg = Wo + (size_t)(col0 + sr) * HD + kt + sce;
    bf16x8 b0 = *(const bf16x8*)(bg);
    bf16x8 b1 = *(const bf16x8*)(bg + 8);
    __syncthreads();
    *(bf16x8*)(As8 + ((sbyte) ^ swz)) = a0;
    *(bf16x8*)(As8 + ((sbyte + 16) ^ swz)) = a1;
    *(bf16x8*)(Bs8 + ((sbyte) ^ swz)) = b0;
    *(bf16x8*)(Bs8 + ((sbyte + 16) ^ swz)) = b1;
    __syncthreads();
    bf16x8 af[4], bfr[4];
#pragma unroll
    for (int mi = 0; mi < 4; mi++) {
      int r = wr + mi * 16 + ln;
      af[mi] = *(const bf16x8*)(As8 + ((r * 64 + lg * 16) ^ ((r & 7) << 4)));
    }
#pragma unroll
    for (int ni = 0; ni < 4; ni++) {
      int r = wc + ni * 16 + ln;
      bfr[ni] = *(const bf16x8*)(Bs8 + ((r * 64 + lg * 16) ^ ((r & 7) << 4)));
    }
#pragma unroll
    for (int mi = 0; mi < 4; mi++)
#pragma unroll
      for (int ni = 0; ni < 4; ni++)
        acc[mi][ni] = mfma16(af[mi], bfr[ni], acc[mi][ni]);
  }

#pragma unroll
  for (int mi = 0; mi < 4; mi++) {
    const int rowb = row0 + wr + mi * 16 + lg * 4;
#pragma unroll
    for (int ni = 0; ni < 4; ni++) {
      const int col = col0 + wc + ni * 16 + ln;
      const float bias = bo[col];
#pragma unroll
      for (int r = 0; r < 4; r++)
        out[(size_t)(rowb + r) * Ee + col] = acc[mi][ni][r] + bias;
    }
  }
}

extern "C" void kernel_launch(void* const* d_in, const int* in_sizes, int n_in,
                              void* d_out, int out_size, void* d_ws, size_t ws_size,
                              hipStream_t stream) {
  (void)in_sizes; (void)n_in; (void)out_size; (void)ws_size;
  const float* kin = (const float*)d_in[1];
  const float* qin = (const float*)d_in[2];
  const float* vin = (const float*)d_in[3];
  const float* Wq = (const float*)d_in[4];
  const float* Wk = (const float*)d_in[5];
  const float* Wv = (const float*)d_in[6];
  const float* Wo = (const float*)d_in[7];
  const float* bo = (const float*)d_in[8];
  float* out = (float*)d_out;

  // ws layout (bf16 elems): wall 1048576 | qh/kh/vt/att 4x4194304 | opart 8388608 | m/l f32
  __bf16* wall = (__bf16*)d_ws;
  __bf16* qh = wall + (size_t)1048576;
  __bf16* kh = qh + (size_t)4194304;
  __bf16* vt = kh + (size_t)4194304;
  __bf16* att = vt + (size_t)4194304;
  __bf16* opart = att + (size_t)4194304;
  float* mpart = (float*)(opart + (size_t)8388608);
  float* lpart = mpart + (size_t)131072;

  cvt_w_kernel<<<dim3(1024), dim3(256), 0, stream>>>(Wq, Wk, Wv, Wo, wall);
  gemm_qkv_kernel<<<dim3(4, 64, 3), dim3(256), 0, stream>>>(qin, kin, vin, wall, qh, kh, vt);
  attn1_kernel<<<dim3(2, 16, 32), dim3(256), 0, stream>>>(qh, kh, vt, opart, mpart, lpart);
  attn2_kernel<<<dim3(256), dim3(256), 0, stream>>>(opart, mpart, lpart, att);
  gemm_out_kernel<<<dim3(4, 64), dim3(256), 0, stream>>>(att, wall + (size_t)3 * 262144, bo, out);
}

// Round 6
// 123.744 us; speedup vs baseline: 1.2608x; 1.2608x over previous
//
#include <hip/hip_runtime.h>
#include <hip/hip_bf16.h>
#include <cstdint>
#include <cstddef>

#define Bb 4
#define Tt 2048
#define Ee 512
#define Hh 8
#define Dd 64
#define HD 512
#define BT 8192

typedef __bf16 bf16x8 __attribute__((ext_vector_type(8)));
typedef __bf16 bf16x4 __attribute__((ext_vector_type(4)));
typedef float f32x4 __attribute__((ext_vector_type(4)));

__device__ __forceinline__ f32x4 mfma16(bf16x8 a, bf16x8 b, f32x4 c) {
  return __builtin_amdgcn_mfma_f32_16x16x32_bf16(a, b, c, 0, 0, 0);
}

typedef __attribute__((address_space(3))) uint32_t lds_u32_t;
typedef const __attribute__((address_space(1))) uint32_t glb_u32_t;
__device__ __forceinline__ void gload16(const void* g, void* l) {
  // wave-uniform LDS base; HW adds lane*16. Global src is per-lane.
  __builtin_amdgcn_global_load_lds((glb_u32_t*)g, (lds_u32_t*)l, 16, 0, 0);
}

// ---- weight conversion: 4 x [512x512] f32 -> bf16 ----
__global__ void cvt_w_kernel(const float* __restrict__ wq, const float* __restrict__ wk,
                             const float* __restrict__ wv, const float* __restrict__ wo,
                             __bf16* __restrict__ dst) {
  int i = (blockIdx.x * 256 + threadIdx.x) * 4;
  int a = i >> 18;
  int off = i & ((1 << 18) - 1);
  const float* src = (a == 0) ? wq : (a == 1) ? wk : (a == 2) ? wv : wo;
  float4 f = *(const float4*)(src + off);
  bf16x4 o;
  o[0] = (__bf16)f.x; o[1] = (__bf16)f.y; o[2] = (__bf16)f.z; o[3] = (__bf16)f.w;
  *(bf16x4*)(dst + i) = o;
}

// ---- QKV projection GEMM. z: 0=Q->qh (pre-scaled by 0.125*log2e), 1=K->kh, 2=V->vt[B,H,D,T] ----
__global__ __launch_bounds__(256)
void gemm_qkv_kernel(const float* __restrict__ Aq, const float* __restrict__ Ak,
                     const float* __restrict__ Av, const __bf16* __restrict__ Wall,
                     __bf16* __restrict__ qh, __bf16* __restrict__ kh, __bf16* __restrict__ vt) {
  const int pz = blockIdx.z;
  const float* A = (pz == 0) ? Aq : (pz == 1) ? Ak : Av;
  const __bf16* Bw = Wall + (size_t)pz * HD * Ee;
  const int row0 = blockIdx.y * 128;
  const int col0 = blockIdx.x * 128;

  __shared__ __align__(16) __bf16 As[128 * 32];
  __shared__ __align__(16) __bf16 Bs[128 * 32];
  char* As8 = (char*)As;
  char* Bs8 = (char*)Bs;

  const int tid = threadIdx.x;
  const int l = tid & 63, w = tid >> 6;
  const int ln = l & 15, lg = l >> 4;
  const int wr = (w >> 1) * 64, wc = (w & 1) * 64;

  const int sr = tid >> 1;
  const int sce = (tid & 1) * 16;
  const int sbyte = sr * 64 + sce * 2;
  const int swz = (sr & 7) << 4;

  f32x4 acc[4][4] = {};

  for (int kt = 0; kt < Ee; kt += 32) {
    const float* ag = A + (size_t)(row0 + sr) * Ee + kt + sce;
    float4 a0 = *(const float4*)(ag);
    float4 a1 = *(const float4*)(ag + 4);
    float4 a2 = *(const float4*)(ag + 8);
    float4 a3 = *(const float4*)(ag + 12);
    const __bf16* bg = Bw + (size_t)(col0 + sr) * Ee + kt + sce;
    bf16x8 b0 = *(const bf16x8*)(bg);
    bf16x8 b1 = *(const bf16x8*)(bg + 8);
    bf16x8 c0, c1;
    c0[0] = (__bf16)a0.x; c0[1] = (__bf16)a0.y; c0[2] = (__bf16)a0.z; c0[3] = (__bf16)a0.w;
    c0[4] = (__bf16)a1.x; c0[5] = (__bf16)a1.y; c0[6] = (__bf16)a1.z; c0[7] = (__bf16)a1.w;
    c1[0] = (__bf16)a2.x; c1[1] = (__bf16)a2.y; c1[2] = (__bf16)a2.z; c1[3] = (__bf16)a2.w;
    c1[4] = (__bf16)a3.x; c1[5] = (__bf16)a3.y; c1[6] = (__bf16)a3.z; c1[7] = (__bf16)a3.w;
    __syncthreads();
    *(bf16x8*)(As8 + ((sbyte) ^ swz)) = c0;
    *(bf16x8*)(As8 + ((sbyte + 16) ^ swz)) = c1;
    *(bf16x8*)(Bs8 + ((sbyte) ^ swz)) = b0;
    *(bf16x8*)(Bs8 + ((sbyte + 16) ^ swz)) = b1;
    __syncthreads();
    bf16x8 af[4], bfr[4];
#pragma unroll
    for (int mi = 0; mi < 4; mi++) {
      int r = wr + mi * 16 + ln;
      af[mi] = *(const bf16x8*)(As8 + ((r * 64 + lg * 16) ^ ((r & 7) << 4)));
    }
#pragma unroll
    for (int ni = 0; ni < 4; ni++) {
      int r = wc + ni * 16 + ln;
      bfr[ni] = *(const bf16x8*)(Bs8 + ((r * 64 + lg * 16) ^ ((r & 7) << 4)));
    }
#pragma unroll
    for (int mi = 0; mi < 4; mi++)
#pragma unroll
      for (int ni = 0; ni < 4; ni++)
        acc[mi][ni] = mfma16(af[mi], bfr[ni], acc[mi][ni]);
  }

  // fold 1/sqrt(D)*log2(e) into Q so attention softmax can use exp2 directly
  const float sc = (pz == 0) ? 0.18033688011112042f : 1.0f;
#pragma unroll
  for (int mi = 0; mi < 4; mi++) {
    const int rowb = row0 + wr + mi * 16 + lg * 4;
    const int bb = rowb >> 11;
    const int t0 = rowb & (Tt - 1);
#pragma unroll
    for (int ni = 0; ni < 4; ni++) {
      const int colb = col0 + wc + ni * 16 + ln;
      const int hh = colb >> 6;
      const int dd = colb & 63;
      if (pz == 2) {
        bf16x4 pk;
#pragma unroll
        for (int r = 0; r < 4; r++) pk[r] = (__bf16)acc[mi][ni][r];
        *(bf16x4*)(vt + ((size_t)(bb * Hh + hh) * Dd + dd) * Tt + t0) = pk;
      } else {
        __bf16* dstp = (pz == 0 ? qh : kh) + ((size_t)(bb * Hh + hh) * Tt + t0) * Dd + dd;
#pragma unroll
        for (int r = 0; r < 4; r++) dstp[(size_t)r * Dd] = (__bf16)(acc[mi][ni][r] * sc);
      }
    }
  }
}

// ---- flash attention pass 1: causal-paired q-tiles + split-K halves ----
// 1024 uniform blocks: block handles q-tiles (p, 31-p); ck takes first/second half
// of each q-tile's KV range -> ~16.5 tiles per block, zero tail. XCD swizzle puts
// all blocks of one bh on XCD bh&7 (K+V of 4 heads = 2MB fits 4MB L2).
// Per-tile body identical to round 4 (52 VGPR, 4 waves x 16 q-rows).
__global__ __launch_bounds__(256)
void attn1_kernel(const __bf16* __restrict__ qh, const __bf16* __restrict__ kh,
                  const __bf16* __restrict__ vt, __bf16* __restrict__ opart,
                  float* __restrict__ mpart, float* __restrict__ lpart) {
  const int j = blockIdx.x;
  const int xcd = j & 7, slot = j >> 3;
  const int ck = slot & 1;
  const int p = (slot >> 1) & 15;
  const int bhi = slot >> 5;
  const int bh = xcd + 8 * bhi;

  __shared__ __align__(16) char Kb[2][8192];  // [64 s][64 d] bf16, XOR-swizzled rows
  __shared__ __align__(16) char Vb[2][8192];  // [64 d][64 t] bf16, XOR-swizzled rows
  __shared__ __align__(16) char Pb[4][2048];  // per-wave [16 q][64 k] bf16, swizzled

  const int tid = threadIdx.x;
  const int l = tid & 63, w = tid >> 6;
  const int ln = l & 15, lg = l >> 4;

  const char* Kg = (const char*)(kh + (size_t)bh * Tt * Dd);
  const char* Vg = (const char*)(vt + (size_t)bh * Dd * Tt);
  const __bf16* Q = qh + (size_t)bh * Tt * Dd;

  const int rsub = l >> 3;                 // 0..7
  const int csw = ((l & 7) ^ rsub) * 16;   // pre-swizzled 16B column
  const int krow = w * 16 + rsub;
  const int swz = (ln & 7) << 4;
  char* P8 = Pb[w];
  const int cb = ck * 32 + bh;

#pragma unroll 1
  for (int ph = 0; ph < 2; ph++) {
    const int qt = ph ? (31 - p) : p;
    const int nlo = qt + 1;               // causal KV tiles for this q-tile
    const int mid = (nlo + 1) >> 1;
    const int tb = ck ? mid : 0;
    const int te = ck ? nlo : mid;
    const int qr = qt * 64 + w * 16;

    __syncthreads();  // prior phase done with LDS buffers

    f32x4 oacc[4] = {};
    float mr = -1e30f, sruml = 0.f;  // per-lane q = qr+ln (replicated over lg)

    if (tb < te) {  // block-uniform
      // prologue: stage tile tb into buffer 0
      {
        const char* kt = Kg + (size_t)tb * 8192;
        const char* vtile = Vg + (size_t)tb * 128;
        char* kb = (char*)Kb[0] + w * 2048;
        char* vb = (char*)Vb[0] + w * 2048;
        gload16(kt + krow * 128 + csw, kb);
        gload16(kt + (krow + 8) * 128 + csw, kb + 1024);
        gload16(vtile + (size_t)krow * 4096 + csw, vb);
        gload16(vtile + (size_t)(krow + 8) * 4096 + csw, vb + 1024);
      }

      bf16x8 qf[2];
#pragma unroll
      for (int kk = 0; kk < 2; kk++)
        qf[kk] = *(const bf16x8*)(Q + (size_t)(qr + ln) * Dd + kk * 32 + lg * 8);

      for (int st = tb; st < te; ++st) {
        const int cur = (st - tb) & 1;
        asm volatile("s_waitcnt vmcnt(0)" ::: "memory");  // own quarter of tile st landed
        __builtin_amdgcn_s_barrier();                     // all waves' quarters landed
        __builtin_amdgcn_sched_barrier(0);
        if (st + 1 < te) {  // prefetch next tile into other buffer
          const char* kt = Kg + (size_t)(st + 1) * 8192;
          const char* vtile = Vg + (size_t)(st + 1) * 128;
          char* kb = (char*)Kb[cur ^ 1] + w * 2048;
          char* vb = (char*)Vb[cur ^ 1] + w * 2048;
          gload16(kt + krow * 128 + csw, kb);
          gload16(kt + (krow + 8) * 128 + csw, kb + 1024);
          gload16(vtile + (size_t)krow * 4096 + csw, vb);
          gload16(vtile + (size_t)(krow + 8) * 4096 + csw, vb + 1024);
        }
        const char* KB = Kb[cur];
        const char* VB = Vb[cur];
        const int s0 = st * 64;

        // swapped QK^T: sacc[ni] holds S[k=s0+ni*16+lg*4+r][q=qr+ln]
        f32x4 sacc[4] = {};
        __builtin_amdgcn_s_setprio(1);
#pragma unroll
        for (int kk = 0; kk < 2; kk++) {
#pragma unroll
          for (int ni = 0; ni < 4; ni++) {
            bf16x8 kf = *(const bf16x8*)(KB + (ni * 16 + ln) * 128 + (((kk * 4 + lg) ^ (ln & 7)) * 16));
            sacc[ni] = mfma16(kf, qf[kk], sacc[ni]);
          }
        }
        __builtin_amdgcn_s_setprio(0);

        if (st == qt) {  // diagonal tile: causal mask (k > q)
#pragma unroll
          for (int ni = 0; ni < 4; ni++)
#pragma unroll
            for (int r = 0; r < 4; r++)
              if ((s0 + ni * 16 + lg * 4 + r) > (qr + ln)) sacc[ni][r] = -1e30f;
        }

        // row max: in-lane over 16, then across lg (2 shfl steps)
        f32x4 m4 = sacc[0];
#pragma unroll
        for (int ni = 1; ni < 4; ni++)
#pragma unroll
          for (int r = 0; r < 4; r++) m4[r] = fmaxf(m4[r], sacc[ni][r]);
        float pmax = fmaxf(fmaxf(m4[0], m4[1]), fmaxf(m4[2], m4[3]));
        pmax = fmaxf(pmax, __shfl_xor(pmax, 16, 64));
        pmax = fmaxf(pmax, __shfl_xor(pmax, 32, 64));

        // defer-max (log2 units, THR=11 -> P bounded by 2^11)
        if (__any(pmax > mr + 11.0f)) {
          float mnew = fmaxf(mr, pmax);
          float facq = exp2f(mr - mnew);
          mr = mnew;
          sruml *= facq;
#pragma unroll
          for (int r = 0; r < 4; r++) {
            float fr = __shfl(facq, lg * 4 + r, 64);  // fac for oacc's q-row
#pragma unroll
            for (int nd = 0; nd < 4; nd++) oacc[nd][r] *= fr;
          }
        }

        // P = exp2(S - m), row sum
        float rsum = 0.f;
#pragma unroll
        for (int ni = 0; ni < 4; ni++)
#pragma unroll
          for (int r = 0; r < 4; r++) {
            float pp = exp2f(sacc[ni][r] - mr);
            sacc[ni][r] = pp;
            rsum += pp;
          }
        rsum += __shfl_xor(rsum, 16, 64);
        rsum += __shfl_xor(rsum, 32, 64);
        sruml += rsum;

        // P -> per-wave LDS, [q=ln][k] rows, b64 packed writes (4 consecutive k)
#pragma unroll
        for (int ni = 0; ni < 4; ni++) {
          bf16x4 pk;
#pragma unroll
          for (int r = 0; r < 4; r++) pk[r] = (__bf16)sacc[ni][r];
          *(bf16x4*)(P8 + ((ln * 128 + ni * 32 + lg * 8) ^ swz)) = pk;
        }
        asm volatile("s_waitcnt lgkmcnt(0)" ::: "memory");
        __builtin_amdgcn_sched_barrier(0);

        // PV: A = P (row=q, k contiguous), B = V^T rows (d), both from LDS
        __builtin_amdgcn_s_setprio(1);
#pragma unroll
        for (int kk = 0; kk < 2; kk++) {
          bf16x8 pf = *(const bf16x8*)(P8 + ((ln * 128 + kk * 64 + lg * 16) ^ swz));
#pragma unroll
          for (int nd = 0; nd < 4; nd++) {
            bf16x8 vf = *(const bf16x8*)(VB + (nd * 16 + ln) * 128 + (((kk * 4 + lg) ^ (ln & 7)) * 16));
            oacc[nd] = mfma16(pf, vf, oacc[nd]);
          }
        }
        __builtin_amdgcn_s_setprio(0);
        asm volatile("s_waitcnt lgkmcnt(0)" ::: "memory");  // P reads done before next overwrite
        __builtin_amdgcn_sched_barrier(0);
      }
    }

    // epilogue: unnormalized O (bf16) + m,l (f32, log2 units); zeros if empty chunk
#pragma unroll
    for (int nd = 0; nd < 4; nd++)
#pragma unroll
      for (int r = 0; r < 4; r++) {
        int t = qr + lg * 4 + r;
        opart[((size_t)cb * Tt + t) * 64 + nd * 16 + ln] = (__bf16)oacc[nd][r];
      }
    if (l < 16) {
      mpart[(size_t)cb * Tt + qr + l] = mr;
      lpart[(size_t)cb * Tt + qr + l] = sruml;
    }
  }
}

// ---- flash attention pass 2: combine the 2 chunks (log2-units m), normalize ----
__global__ __launch_bounds__(256)
void attn2_kernel(const __bf16* __restrict__ opart, const float* __restrict__ mpart,
                  const float* __restrict__ lpart, __bf16* __restrict__ att) {
  int idx = blockIdx.x * 256 + threadIdx.x;  // row id over [bh=32][t=2048]
  int bh = idx >> 11, t = idx & (Tt - 1);
  int b = bh >> 3, h = bh & 7;
  const __bf16* o0 = opart + ((size_t)bh * Tt + t) * 64;
  const __bf16* o1 = o0 + (size_t)32 * Tt * 64;
  __bf16* dst = att + ((size_t)(b * Tt + t)) * HD + h * 64;
  float m0 = mpart[(size_t)bh * Tt + t];
  float l0 = lpart[(size_t)bh * Tt + t];
  float m1 = mpart[(size_t)(32 + bh) * Tt + t];
  float l1 = lpart[(size_t)(32 + bh) * Tt + t];
  float M = fmaxf(m0, m1);
  float e0 = exp2f(m0 - M), e1 = exp2f(m1 - M);
  float den = l0 * e0 + l1 * e1;
  float a0 = e0 / den, a1 = e1 / den;
#pragma unroll
  for (int jj = 0; jj < 8; jj++) {
    bf16x8 v0 = ((const bf16x8*)o0)[jj];
    bf16x8 v1 = ((const bf16x8*)o1)[jj];
    bf16x8 o;
#pragma unroll
    for (int e = 0; e < 8; e++)
      o[e] = (__bf16)((float)v0[e] * a0 + (float)v1[e] * a1);
    ((bf16x8*)dst)[jj] = o;
  }
}

// ---- output projection: att[8192x512] bf16 x Wo[512x512] bf16 ([N][K]) + bo -> f32 ----
__global__ __launch_bounds__(256)
void gemm_out_kernel(const __bf16* __restrict__ att, const __bf16* __restrict__ Wo,
                     const float* __restrict__ bo, float* __restrict__ out) {
  const int row0 = blockIdx.y * 128;
  const int col0 = blockIdx.x * 128;
  __shared__ __align__(16) __bf16 As[128 * 32];
  __shared__ __align__(16) __bf16 Bs[128 * 32];
  char* As8 = (char*)As;
  char* Bs8 = (char*)Bs;
  const int tid = threadIdx.x;
  const int l = tid & 63, w = tid >> 6;
  const int ln = l & 15, lg = l >> 4;
  const int wr = (w >> 1) * 64, wc = (w & 1) * 64;
  const int sr = tid >> 1;
  const int sce = (tid & 1) * 16;
  const int sbyte = sr * 64 + sce * 2;
  const int swz = (sr & 7) << 4;
  f32x4 acc[4][4] = {};

  for (int kt = 0; kt < HD; kt += 32) {
    const __bf16* ag = att + (size_t)(row0 + sr) * HD + kt + sce;
    bf16x8 a0 = *(const bf16x8*)(ag);
    bf16x8 a1 = *(const bf16x8*)(ag + 8);
    const __bf16* bg = Wo + (size_t)(col0 + sr) * HD + kt + sce;
    bf16x8 b0 = *(const bf16x8*)(bg);
    bf16x8 b1 = *(const bf16x8*)(bg + 8);
    __syncthreads();
    *(bf16x8*)(As8 + ((sbyte) ^ swz)) = a0;
    *(bf16x8*)(As8 + ((sbyte + 16) ^ swz)) = a1;
    *(bf16x8*)(Bs8 + ((sbyte) ^ swz)) = b0;
    *(bf16x8*)(Bs8 + ((sbyte + 16) ^ swz)) = b1;
    __syncthreads();
    bf16x8 af[4], bfr[4];
#pragma unroll
    for (int mi = 0; mi < 4; mi++) {
      int r = wr + mi * 16 + ln;
      af[mi] = *(const bf16x8*)(As8 + ((r * 64 + lg * 16) ^ ((r & 7) << 4)));
    }
#pragma unroll
    for (int ni = 0; ni < 4; ni++) {
      int r = wc + ni * 16 + ln;
      bfr[ni] = *(const bf16x8*)(Bs8 + ((r * 64 + lg * 16) ^ ((r & 7) << 4)));
    }
#pragma unroll
    for (int mi = 0; mi < 4; mi++)
#pragma unroll
      for (int ni = 0; ni < 4; ni++)
        acc[mi][ni] = mfma16(af[mi], bfr[ni], acc[mi][ni]);
  }

#pragma unroll
  for (int mi = 0; mi < 4; mi++) {
    const int rowb = row0 + wr + mi * 16 + lg * 4;
#pragma unroll
    for (int ni = 0; ni < 4; ni++) {
      const int col = col0 + wc + ni * 16 + ln;
      const float bias = bo[col];
#pragma unroll
      for (int r = 0; r < 4; r++)
        out[(size_t)(rowb + r) * Ee + col] = acc[mi][ni][r] + bias;
    }
  }
}

extern "C" void kernel_launch(void* const* d_in, const int* in_sizes, int n_in,
                              void* d_out, int out_size, void* d_ws, size_t ws_size,
                              hipStream_t stream) {
  (void)in_sizes; (void)n_in; (void)out_size; (void)ws_size;
  const float* kin = (const float*)d_in[1];
  const float* qin = (const float*)d_in[2];
  const float* vin = (const float*)d_in[3];
  const float* Wq = (const float*)d_in[4];
  const float* Wk = (const float*)d_in[5];
  const float* Wv = (const float*)d_in[6];
  const float* Wo = (const float*)d_in[7];
  const float* bo = (const float*)d_in[8];
  float* out = (float*)d_out;

  // ws layout (bf16 elems): wall 1048576 | qh/kh/vt/att 4x4194304 | opart 8388608 | m/l f32
  __bf16* wall = (__bf16*)d_ws;
  __bf16* qh = wall + (size_t)1048576;
  __bf16* kh = qh + (size_t)4194304;
  __bf16* vt = kh + (size_t)4194304;
  __bf16* att = vt + (size_t)4194304;
  __bf16* opart = att + (size_t)4194304;
  float* mpart = (float*)(opart + (size_t)8388608);
  float* lpart = mpart + (size_t)131072;

  cvt_w_kernel<<<dim3(1024), dim3(256), 0, stream>>>(Wq, Wk, Wv, Wo, wall);
  gemm_qkv_kernel<<<dim3(4, 64, 3), dim3(256), 0, stream>>>(qin, kin, vin, wall, qh, kh, vt);
  attn1_kernel<<<dim3(1024), dim3(256), 0, stream>>>(qh, kh, vt, opart, mpart, lpart);
  attn2_kernel<<<dim3(256), dim3(256), 0, stream>>>(opart, mpart, lpart, att);
  gemm_out_kernel<<<dim3(4, 64), dim3(256), 0, stream>>>(att, wall + (size_t)3 * 262144, bo, out);
}